// Round 7
// baseline (292.405 us; speedup 1.0000x reference)
//
#include <hip/hip_runtime.h>
#include <stdint.h>

typedef unsigned int  u32;
typedef unsigned short u16;
typedef __bf16 v8bf __attribute__((ext_vector_type(8)));
typedef float  v4f  __attribute__((ext_vector_type(4)));

#define N_INST 256
#define BATCH  128
#define IN_DIM 1024
#define L_DIM  512
#define M_TOT  (N_INST*BATCH)   // 32768
#define NSLICE 16               // 16 colslices (64 pcols each)

// Fragment-tiled layouts (u16 units). Region = 1 KB = 64 lanes x 16 B.
// A (xb): region = mblk*256 + kt*16 + g*2 + kk   (g=row-group 0..7)
//   lane(q,c): row = mblk*128 + g*16 + c, k = kt*64 + kk*32 + q*8
// B (wpk): region = cs*128 + kt*8 + j*2 + kk     (cs=colslice 0..15, j=0..3)
//   lane(q,c): packed col p = cs*64 + j*16 + c, k = kt*64 + kk*32 + q*8
//   bcol = p>>4 = cs*4+j (even=V, odd=U), l = (bcol>>1)*16 + c
// ws: [0,64MB) xb; [64MB,66MB) wpk; [66MB,68MB) partial [16][M_TOT]
#define XB_BYTES   ((size_t)M_TOT * IN_DIM * 2)
#define WPK_BYTES  ((size_t)1024 * IN_DIM * 2)

__device__ inline u32 f2bf_pk(float a, float b){
  u32 ua = __builtin_bit_cast(u32, a);
  u32 ub = __builtin_bit_cast(u32, b);
  ua = (ua + 0x7FFFu + ((ua >> 16) & 1u)) >> 16;
  ub = (ub + 0x7FFFu + ((ub >> 16) & 1u)) & 0xFFFF0000u;
  return ua | ub;
}

__device__ inline void gl2lds16(const u16* g, u16* l){
  __builtin_amdgcn_global_load_lds(
      (const __attribute__((address_space(1))) u32*)(g),
      (__attribute__((address_space(3))) u32*)(l), 16, 0, 0);
}

#define PREP_XBLKS 16384
__global__ void prep(const float* __restrict__ x, const float* __restrict__ v,
                     const float* __restrict__ u, u16* __restrict__ xb,
                     u16* __restrict__ wpk){
  const int b = blockIdx.x;
  if (b < PREP_XBLKS){
    int t = b * 256 + threadIdx.x;
    int r = t >> 6, l = t & 63;
    int kk = r & 1, i = (r >> 1) & 3, h = (r >> 3) & 1, kt = (r >> 4) & 15, mb = r >> 8;
    int q = l >> 4, c = l & 15;
    int row = mb*128 + h*64 + i*16 + c;
    int k0  = kt*64 + kk*32 + q*8;
    const float* src = x + (size_t)row * IN_DIM + k0;
    float4 a0 = *reinterpret_cast<const float4*>(src);
    float4 a1 = *reinterpret_cast<const float4*>(src + 4);
    uint4 out;
    out.x = f2bf_pk(a0.x, a0.y); out.y = f2bf_pk(a0.z, a0.w);
    out.z = f2bf_pk(a1.x, a1.y); out.w = f2bf_pk(a1.z, a1.w);
    *reinterpret_cast<uint4*>(xb + (size_t)r*512 + l*8) = out;
  } else {
    int t = (b - PREP_XBLKS) * 256 + threadIdx.x;   // 131072 threads
    int r = t >> 6, l = t & 63;
    int kk = r & 1, j = (r >> 1) & 3, kt = (r >> 3) & 15, cs = r >> 7;
    int q = l >> 4, c = l & 15;
    int bcol = cs*4 + j;
    const float* src = (bcol & 1) ? u : v;
    int lcol = (bcol >> 1)*16 + c;
    int k0 = kt*64 + kk*32 + q*8;
    u32 o[4];
#pragma unroll
    for (int ii = 0; ii < 4; ++ii){
      float a  = src[(size_t)(k0 + 2*ii    ) * L_DIM + lcol];
      float bb = src[(size_t)(k0 + 2*ii + 1) * L_DIM + lcol];
      o[ii] = f2bf_pk(a, bb);
    }
    *reinterpret_cast<uint4*>(wpk + (size_t)r*512 + l*8) = make_uint4(o[0], o[1], o[2], o[3]);
  }
}

// ---- gemm_score: 256 rows x 128 pcols per block, 8 waves (4M x 2N), A+B in LDS ----
// A shared through LDS (staged once per block, read by both N-waves) -> per-CU L2
// demand drops to ~39 B/cyc (< ~56 ceiling). LDS dbuf 2 x 48 KB (A 32 + B 16 per kt).
// 1 block/CU, 2 waves/SIMD @ 256 regs -> no spill possible. One raw barrier per kt;
// stage issued right after the barrier so the vmcnt(0) drain at next kt is ~free.
// LDS regions per buf: A: r = mloc*16 + g*2 + kk (0..31); B: 32 + csloc*8 + j*2 + kk.

#define STAGE(KT, LB) { _Pragma("unroll") for (int it_ = 0; it_ < 6; ++it_)           \
    gl2lds16(sp[it_] + (size_t)(KT)*sstr[it_], &Ls[(LB) + (wave*6+it_)*512]); }

#define LOADA_F(P, LB, KK) { _Pragma("unroll") for (int gi_ = 0; gi_ < 4; ++gi_)      \
    afb[P][gi_] = *reinterpret_cast<const v8bf*>(&Ls[(LB) + ao0 + (gi_*2+(KK))*512]); }

#define LOADB_F(P, LB, KK) { _Pragma("unroll") for (int j_ = 0; j_ < 4; ++j_)         \
    bfb[P][j_] = *reinterpret_cast<const v8bf*>(&Ls[(LB) + bo0 + (j_*2+(KK))*512]); }

// One kk-step on frag-buffer P; if DO_R, refill P^1 with (NKK) frags (same LDS buf),
// b-frags right after their last MFMA reader, a-frags after the cluster.
#define STEPX(P, DO_R, LB, NKK) {                                                     \
  __builtin_amdgcn_s_setprio(1);                                                      \
  _Pragma("unroll") for (int j_ = 0; j_ < 4; ++j_){                                   \
    _Pragma("unroll") for (int gi_ = 0; gi_ < 4; ++gi_)                               \
      acc[gi_][j_] = __builtin_amdgcn_mfma_f32_16x16x32_bf16(                         \
          afb[P][gi_], bfb[P][j_], acc[gi_][j_], 0, 0, 0);                            \
    if (DO_R) bfb[(P)^1][j_] = *reinterpret_cast<const v8bf*>(                        \
        &Ls[(LB) + bo0 + (j_*2+(NKK))*512]);                                          \
  }                                                                                   \
  __builtin_amdgcn_s_setprio(0);                                                      \
  if (DO_R) LOADA_F((P)^1, LB, NKK); }

#define WAIT_BAR {                                                                    \
  __builtin_amdgcn_sched_barrier(0);                                                  \
  asm volatile("s_waitcnt vmcnt(0)" ::: "memory");                                    \
  __builtin_amdgcn_s_barrier();                                                       \
  __builtin_amdgcn_sched_barrier(0); }

__launch_bounds__(512, 2)
__global__ void gemm_score(const u16* __restrict__ xb, const u16* __restrict__ wpk,
                           const float* __restrict__ w, float* __restrict__ partial){
  __shared__ __align__(16) u16 Ls[2*48*512];   // 96 KB: [buf][region 0..47][512]

  const int tid  = threadIdx.x;
  const u32 bid  = blockIdx.x;            // 0..1023
  // bid = 64*hi + 8*csp + lo : lo = XCD (consecutive bids round-robin XCDs), so all
  // 8 csp of one M-panel sit on the same XCD concurrently -> A panel is L2-local.
  const int lo  = bid & 7;
  const int csp = (bid >> 3) & 7;         // 128-pcol slice pair 0..7
  const int hi  = bid >> 6;               // 0..15
  const int m   = lo*16 + hi;             // M-panel 0..127 (256 rows each)
  const int mblk0 = m*2;

  const int lane = tid & 63;
  const int wave = tid >> 6;              // 0..7
  const int q    = lane >> 4;
  const int c    = lane & 15;
  const int wm   = wave >> 1;             // 0..3: 64-row group
  const int wn   = wave & 1;              // 0..1: 64-pcol group

  // per-wave stage sources: regions r = wave*6 .. wave*6+5 of the 48-region kt-tile
  const u16* sp[6]; u32 sstr[6];
#pragma unroll
  for (int it = 0; it < 6; ++it){
    int r = wave*6 + it;
    if (r < 32){                          // A region: mloc = r>>4, (g*2+kk) = r&15
      sp[it]   = xb + ((size_t)(mblk0 + (r>>4))*256 + (r&15))*512 + lane*8;
      sstr[it] = 16*512;                  // kt stride in u16
    } else {                              // B region: csloc = (r-32)>>3, rem = (r-32)&7
      int rb = r - 32;
      sp[it]   = wpk + ((size_t)((csp*2 + (rb>>3))*128 + (rb&7)))*512 + lane*8;
      sstr[it] = 8*512;
    }
  }

  // frag read bases (u16 offsets within an LDS buf)
  const u32 ao0 = (u32)(((wm>>1)*16 + (wm&1)*8)*512) + lane*8;  // + (gi*2+kk)*512
  const u32 bo0 = (u32)((32 + wn*8)*512) + lane*8;              // + (j*2+kk)*512

  v8bf afb[2][4];
  v8bf bfb[2][4];
  v4f  acc[4][4];
#pragma unroll
  for (int gi = 0; gi < 4; ++gi)
#pragma unroll
    for (int j = 0; j < 4; ++j)
      acc[gi][j] = (v4f){0.f, 0.f, 0.f, 0.f};

  STAGE(0, 0);
  u32 lb = 0;

#pragma unroll 1
  for (int kt = 0; kt < 16; ++kt){
    WAIT_BAR;                        // buf[lb] staged; all waves past prior reads
    if (kt < 15) STAGE(kt+1, lb ^ 24576);
    LOADA_F(0, lb, 0); LOADB_F(0, lb, 0);
    STEPX(0, 1, lb, 1);              // compute kk0; refill P1 <- kk1
    STEPX(1, 0, lb, 0);              // compute kk1
    lb ^= 24576;
  }

  // epilogue: this wave owns rows [m*256 + wm*64, +64), cs = csp*2 + wn
  const int cs = csp*2 + wn;
  const float wl0 = w[cs*32 + c];
  const float wl1 = w[cs*32 + 16 + c];
  float* pout = partial + (size_t)cs * M_TOT + (size_t)m*256 + wm*64;

#pragma unroll
  for (int gi = 0; gi < 4; ++gi){
#pragma unroll
    for (int r = 0; r < 4; ++r){
      float t0 = 2.f / (1.f + __expf(-2.f * acc[gi][0][r])) - 1.f;
      float s0 = 1.f / (1.f + __expf(-acc[gi][1][r]));
      float t1 = 2.f / (1.f + __expf(-2.f * acc[gi][2][r])) - 1.f;
      float s1 = 1.f / (1.f + __expf(-acc[gi][3][r]));
      float v2 = t0*s0*wl0 + t1*s1*wl1;
      v2 += __shfl_xor(v2, 1, 64);
      v2 += __shfl_xor(v2, 2, 64);
      v2 += __shfl_xor(v2, 4, 64);
      v2 += __shfl_xor(v2, 8, 64);
      if (c == 0) pout[gi*16 + q*4 + r] = v2;   // slice-private rows
    }
  }
}

__global__ void softmax_inst(const float* __restrict__ partial, float* __restrict__ out){
  __shared__ float red[N_INST];
  const int b = blockIdx.x;
  const int n = threadIdx.x;
  float s = 0.f;
#pragma unroll
  for (int i = 0; i < NSLICE; ++i) s += partial[(size_t)i * M_TOT + n*BATCH + b];
  red[n] = s; __syncthreads();
  for (int st = N_INST/2; st > 0; st >>= 1){
    if (n < st) red[n] = fmaxf(red[n], red[n + st]);
    __syncthreads();
  }
  float mx = red[0]; __syncthreads();
  float e = __expf(s - mx);
  red[n] = e; __syncthreads();
  for (int st = N_INST/2; st > 0; st >>= 1){
    if (n < st) red[n] += red[n + st];
    __syncthreads();
  }
  out[n*BATCH + b] = e / red[0];
}

extern "C" void kernel_launch(void* const* d_in, const int* in_sizes, int n_in,
                              void* d_out, int out_size, void* d_ws, size_t ws_size,
                              hipStream_t stream) {
  const float* x = (const float*)d_in[0];
  const float* v = (const float*)d_in[1];
  const float* u = (const float*)d_in[2];
  const float* w = (const float*)d_in[3];
  u16*   xb      = (u16*)d_ws;
  u16*   wpk     = (u16*)((char*)d_ws + XB_BYTES);
  float* partial = (float*)((char*)d_ws + XB_BYTES + WPK_BYTES);
  float* out     = (float*)d_out;

  prep<<<dim3(PREP_XBLKS + 512), dim3(256), 0, stream>>>(x, v, u, xb, wpk);
  gemm_score<<<dim3(1024), dim3(512), 0, stream>>>(xb, wpk, w, partial);
  softmax_inst<<<dim3(BATCH), dim3(N_INST), 0, stream>>>(partial, out);
}

// Round 8
// 288.069 us; speedup vs baseline: 1.0151x; 1.0151x over previous
//
#include <hip/hip_runtime.h>
#include <stdint.h>

typedef unsigned int  u32;
typedef unsigned short u16;
typedef __bf16 v8bf __attribute__((ext_vector_type(8)));
typedef float  v4f  __attribute__((ext_vector_type(4)));

#define N_INST 256
#define BATCH  128
#define IN_DIM 1024
#define L_DIM  512
#define M_TOT  (N_INST*BATCH)   // 32768
#define NSLICE 16               // 16 colslices (64 pcols each)

// Fragment-tiled layouts (u16 units). Region = 1 KB = 64 lanes x 16 B.
// A (xb): region = mblk*256 + kt*16 + g*2 + kk   (g=row-group 0..7)
//   lane(q,c): row = mblk*128 + g*16 + c, k = kt*64 + kk*32 + q*8
// B (wpk): region = cs*128 + kt*8 + j*2 + kk     (cs=colslice 0..15, j=0..3)
//   lane(q,c): packed col p = cs*64 + j*16 + c, k = kt*64 + kk*32 + q*8
//   bcol = p>>4 = cs*4+j (even=V, odd=U), l = (bcol>>1)*16 + c
// ws: [0,64MB) xb; [64MB,66MB) wpk; [66MB,68MB) partial [16][M_TOT]
#define XB_BYTES   ((size_t)M_TOT * IN_DIM * 2)
#define WPK_BYTES  ((size_t)1024 * IN_DIM * 2)

__device__ inline u32 f2bf_pk(float a, float b){
  u32 ua = __builtin_bit_cast(u32, a);
  u32 ub = __builtin_bit_cast(u32, b);
  ua = (ua + 0x7FFFu + ((ua >> 16) & 1u)) >> 16;
  ub = (ub + 0x7FFFu + ((ub >> 16) & 1u)) & 0xFFFF0000u;
  return ua | ub;
}

__device__ inline void gl2lds16(const u16* g, u16* l){
  __builtin_amdgcn_global_load_lds(
      (const __attribute__((address_space(1))) u32*)(g),
      (__attribute__((address_space(3))) u32*)(l), 16, 0, 0);
}

#define PREP_XBLKS 16384
__global__ void prep(const float* __restrict__ x, const float* __restrict__ v,
                     const float* __restrict__ u, u16* __restrict__ xb,
                     u16* __restrict__ wpk){
  const int b = blockIdx.x;
  if (b < PREP_XBLKS){
    int t = b * 256 + threadIdx.x;
    int r = t >> 6, l = t & 63;
    int kk = r & 1, i = (r >> 1) & 3, h = (r >> 3) & 1, kt = (r >> 4) & 15, mb = r >> 8;
    int q = l >> 4, c = l & 15;
    int row = mb*128 + h*64 + i*16 + c;
    int k0  = kt*64 + kk*32 + q*8;
    const float* src = x + (size_t)row * IN_DIM + k0;
    float4 a0 = *reinterpret_cast<const float4*>(src);
    float4 a1 = *reinterpret_cast<const float4*>(src + 4);
    uint4 out;
    out.x = f2bf_pk(a0.x, a0.y); out.y = f2bf_pk(a0.z, a0.w);
    out.z = f2bf_pk(a1.x, a1.y); out.w = f2bf_pk(a1.z, a1.w);
    *reinterpret_cast<uint4*>(xb + (size_t)r*512 + l*8) = out;
  } else {
    int t = (b - PREP_XBLKS) * 256 + threadIdx.x;   // 131072 threads
    int r = t >> 6, l = t & 63;
    int kk = r & 1, j = (r >> 1) & 3, kt = (r >> 3) & 15, cs = r >> 7;
    int q = l >> 4, c = l & 15;
    int bcol = cs*4 + j;
    const float* src = (bcol & 1) ? u : v;
    int lcol = (bcol >> 1)*16 + c;
    int k0 = kt*64 + kk*32 + q*8;
    u32 o[4];
#pragma unroll
    for (int ii = 0; ii < 4; ++ii){
      float a  = src[(size_t)(k0 + 2*ii    ) * L_DIM + lcol];
      float bb = src[(size_t)(k0 + 2*ii + 1) * L_DIM + lcol];
      o[ii] = f2bf_pk(a, bb);
    }
    *reinterpret_cast<uint4*>(wpk + (size_t)r*512 + l*8) = make_uint4(o[0], o[1], o[2], o[3]);
  }
}

// ---- gemm_score: 256 rows x 128 pcols, 8 waves (4M x 2N), A+B LDS, ring-3 ----
// kk-granular buffers: 24 regions = 24 KB (A 16: mloc*8+g; B 16+csloc*4+j).
// Ring of 3 (72 KB) -> 2 blocks/CU. Per step s: STAGE(s+2) -> frags(s) -> 16 MFMA
// -> vmcnt(3) + s_barrier (counted: newest stage stays in flight; older confirmed).
// Frags single-buffered (32 VGPR); acc 64 AGPR; launch_bounds(512,4) -> 4 waves/SIMD.

#define STAGE_P(KKC, RB) { _Pragma("unroll") for (int it_ = 0; it_ < 3; ++it_)        \
    gl2lds16(sp[it_] + (KKC)*512, &Ls[(RB) + (wave3 + it_)*512]); }

#define STAGE_N(KKC, RB) { _Pragma("unroll") for (int it_ = 0; it_ < 3; ++it_)        \
    gl2lds16(sp[it_] + sstr[it_] + (KKC)*512, &Ls[(RB) + (wave3 + it_)*512]); }

#define FRAGS(RB) {                                                                   \
  _Pragma("unroll") for (int gi_ = 0; gi_ < 4; ++gi_)                                 \
    afb[gi_] = *reinterpret_cast<const v8bf*>(&Ls[(RB) + ao0 + gi_*512]);             \
  _Pragma("unroll") for (int j_ = 0; j_ < 4; ++j_)                                    \
    bfb[j_] = *reinterpret_cast<const v8bf*>(&Ls[(RB) + bo0 + j_*512]); }

#define MFMA16 {                                                                      \
  __builtin_amdgcn_s_setprio(1);                                                      \
  _Pragma("unroll") for (int j_ = 0; j_ < 4; ++j_)                                    \
    _Pragma("unroll") for (int gi_ = 0; gi_ < 4; ++gi_)                               \
      acc[gi_][j_] = __builtin_amdgcn_mfma_f32_16x16x32_bf16(                         \
          afb[gi_], bfb[j_], acc[gi_][j_], 0, 0, 0);                                  \
  __builtin_amdgcn_s_setprio(0); }

#define BARC(N) {                                                                     \
  __builtin_amdgcn_sched_barrier(0);                                                  \
  asm volatile("s_waitcnt vmcnt(" #N ")" ::: "memory");                               \
  __builtin_amdgcn_s_barrier();                                                       \
  __builtin_amdgcn_sched_barrier(0); }

__launch_bounds__(512, 4)
__global__ void gemm_score(const u16* __restrict__ xb, const u16* __restrict__ wpk,
                           const float* __restrict__ w, float* __restrict__ partial){
  __shared__ __align__(16) u16 Ls[3*24*512];   // 72 KB: 3 ring buffers x 24 regions

  const int tid  = threadIdx.x;
  const u32 bid  = blockIdx.x;            // 0..1023
  // bid = 64*hi + 8*csp + lo : lo = XCD, so all 8 csp of an M-panel share an XCD.
  const int lo  = bid & 7;
  const int csp = (bid >> 3) & 7;         // 128-pcol slice pair 0..7
  const int hi  = bid >> 6;               // 0..15
  const int m   = lo*16 + hi;             // M-panel 0..127 (256 rows each)
  const int mblk0 = m*2;

  const int lane = tid & 63;
  const int wave = tid >> 6;              // 0..7
  const int wave3= wave*3;
  const int q    = lane >> 4;
  const int c    = lane & 15;
  const int wm   = wave >> 1;             // 0..3: 64-row group
  const int wn   = wave & 1;              // 0..1: 64-pcol group

  // stage sources: wave covers buffer-regions 3w..3w+2 (A: r<16, B: r>=16), kt=0,kk=0
  const u16* sp[3]; u32 sstr[3];
#pragma unroll
  for (int it = 0; it < 3; ++it){
    int r = wave3 + it;
    if (r < 16){                          // A: mloc = r>>3, g = r&7
      sp[it]   = xb + ((size_t)(mblk0 + (r>>3))*256 + (r&7)*2)*512 + lane*8;
      sstr[it] = 16*512;                  // kt stride (u16)
    } else {                              // B: csloc = (r-16)>>2, j = (r-16)&3
      int rb_ = r - 16;
      sp[it]   = wpk + ((size_t)((csp*2 + (rb_>>2))*128 + (rb_&3)*2))*512 + lane*8;
      sstr[it] = 8*512;
    }
  }

  // frag read bases (u16 offsets within a ring buffer)
  const u32 ao0 = (u32)(((wm>>1)*8 + (wm&1)*4)*512) + lane*8;  // + gi*512
  const u32 bo0 = (u32)((16 + wn*4)*512) + lane*8;             // + j*512

  v8bf afb[4];
  v8bf bfb[4];
  v4f  acc[4][4];
#pragma unroll
  for (int gi = 0; gi < 4; ++gi)
#pragma unroll
    for (int j = 0; j < 4; ++j)
      acc[gi][j] = (v4f){0.f, 0.f, 0.f, 0.f};

  u32 rb0 = 0, rb1 = 12288, rb2 = 24576;  // ring bases (u16 units, 24 KB apart)

  STAGE_P(0, rb0);                 // step 0 (kt=0, kk=0)
  STAGE_P(1, rb1);                 // step 1 (kt=0, kk=1)
  BARC(3);                         // step 0 confirmed (newest 3 = step 1)

#pragma unroll 1
  for (int kt = 0; kt < 15; ++kt){
    // step 2kt: compute rb0, stage step 2kt+2 -> rb2
    STAGE_N(0, rb2);
    FRAGS(rb0);
    MFMA16;
    BARC(3);                       // step 2kt+1 (rb1) confirmed
    // step 2kt+1: compute rb1, stage step 2kt+3 -> rb0 (reads of rb0 done block-wide)
    STAGE_N(1, rb0);
    FRAGS(rb1);
    MFMA16;
    BARC(3);                       // step 2kt+2 (rb2) confirmed
    { u32 t = rb0; rb0 = rb2; rb2 = rb1; rb1 = t; }   // (rb0,rb1,rb2) <- (rb2,rb0,rb1)
#pragma unroll
    for (int it = 0; it < 3; ++it) sp[it] += sstr[it];
  }
  // tail kt=15: rb0 = step 30 (confirmed); rb1 = step 31 (needs drain)
  FRAGS(rb0);
  MFMA16;
  BARC(0);                         // only full drain, once
  FRAGS(rb1);
  MFMA16;

  // epilogue: this wave owns rows [m*256 + wm*64, +64), cs = csp*2 + wn
  const int cs = csp*2 + wn;
  const float wl0 = w[cs*32 + c];
  const float wl1 = w[cs*32 + 16 + c];
  float* pout = partial + (size_t)cs * M_TOT + (size_t)m*256 + wm*64;

#pragma unroll
  for (int gi = 0; gi < 4; ++gi){
#pragma unroll
    for (int r = 0; r < 4; ++r){
      float t0 = 2.f / (1.f + __expf(-2.f * acc[gi][0][r])) - 1.f;
      float s0 = 1.f / (1.f + __expf(-acc[gi][1][r]));
      float t1 = 2.f / (1.f + __expf(-2.f * acc[gi][2][r])) - 1.f;
      float s1 = 1.f / (1.f + __expf(-acc[gi][3][r]));
      float v2 = t0*s0*wl0 + t1*s1*wl1;
      v2 += __shfl_xor(v2, 1, 64);
      v2 += __shfl_xor(v2, 2, 64);
      v2 += __shfl_xor(v2, 4, 64);
      v2 += __shfl_xor(v2, 8, 64);
      if (c == 0) pout[gi*16 + q*4 + r] = v2;   // slice-private rows
    }
  }
}

__global__ void softmax_inst(const float* __restrict__ partial, float* __restrict__ out){
  __shared__ float red[N_INST];
  const int b = blockIdx.x;
  const int n = threadIdx.x;
  float s = 0.f;
#pragma unroll
  for (int i = 0; i < NSLICE; ++i) s += partial[(size_t)i * M_TOT + n*BATCH + b];
  red[n] = s; __syncthreads();
  for (int st = N_INST/2; st > 0; st >>= 1){
    if (n < st) red[n] = fmaxf(red[n], red[n + st]);
    __syncthreads();
  }
  float mx = red[0]; __syncthreads();
  float e = __expf(s - mx);
  red[n] = e; __syncthreads();
  for (int st = N_INST/2; st > 0; st >>= 1){
    if (n < st) red[n] += red[n + st];
    __syncthreads();
  }
  out[n*BATCH + b] = e / red[0];
}

extern "C" void kernel_launch(void* const* d_in, const int* in_sizes, int n_in,
                              void* d_out, int out_size, void* d_ws, size_t ws_size,
                              hipStream_t stream) {
  const float* x = (const float*)d_in[0];
  const float* v = (const float*)d_in[1];
  const float* u = (const float*)d_in[2];
  const float* w = (const float*)d_in[3];
  u16*   xb      = (u16*)d_ws;
  u16*   wpk     = (u16*)((char*)d_ws + XB_BYTES);
  float* partial = (float*)((char*)d_ws + XB_BYTES + WPK_BYTES);
  float* out     = (float*)d_out;

  prep<<<dim3(PREP_XBLKS + 512), dim3(256), 0, stream>>>(x, v, u, xb, wpk);
  gemm_score<<<dim3(1024), dim3(512), 0, stream>>>(xb, wpk, w, partial);
  softmax_inst<<<dim3(BATCH), dim3(N_INST), 0, stream>>>(partial, out);
}